// Round 5
// baseline (138.651 us; speedup 1.0000x reference)
//
#include <hip/hip_runtime.h>
#include <hip/hip_bf16.h>
#include <math.h>

// SupConLoss, B=4096 V=2 D=128, N=8192.
// loss = (1/N) [ sum_i log(sum_{j!=i} exp(n_i.n_j/T)) - 2*sum_b spos_b ]
// Round 5: exploit symmetry of S = n.n^T. Only upper-triangular 256x256
// group-pair tiles (528 blocks, 52% of full work); each tile yields row-sums
// (rows of gi) AND col-sums (rows of gj). final_k parallel (32 blocks +
// atomicAdd). No device-scope fences anywhere (R3 lesson).

constexpr int   Bsz   = 4096;
constexpr int   Nrows = 8192;
constexpr int   Dd    = 128;
constexpr float TEMPf = 0.07f;
constexpr float EPSN  = 1e-8f;
constexpr float SCALE = 1.4426950408889634f / 0.07f;  // log2(e)/T
constexpr float LN2   = 0.6931471805599453f;

constexpr int G          = 32;                 // row groups of 256
constexpr int NBLK       = G * (G + 1) / 2;    // 528 upper-tri pairs
constexpr int TILE_COLS  = 64;
constexpr int TILE_BYTES = TILE_COLS * 256;    // 16 KB
constexpr int PREPBLKS   = Bsz / 4;            // 1024

typedef __attribute__((ext_vector_type(8)))  short bf16x8;   // 8 bf16 = 4 VGPRs
typedef __attribute__((ext_vector_type(16))) float floatx16; // MFMA 32x32 C/D

// ws layout (bytes):
//   0x000000  nB   bf16[8192][128]   2 MB
//   0x200000  nA   bf16[8192][128]   2 MB  (pre-scaled by SCALE)
//   0x400000  partial f32[32][8192]  1 MB   (slot = partner group)
//   0x500000  sposPart f32[1024]     4 KB
constexpr size_t OFF_NA   = 0x200000;
constexpr size_t OFF_PART = 0x400000;
constexpr size_t OFF_SPOS = 0x500000;

// ------------- prep: normalize both views + per-block spos sums ----------------
__global__ void prep_k(const float* __restrict__ f,
                       __hip_bfloat16* __restrict__ nB,
                       __hip_bfloat16* __restrict__ nA,
                       float* __restrict__ sposPart,
                       float* __restrict__ out) {
    __shared__ float sred[4];
    int tid  = threadIdx.x;
    int wid  = tid >> 6;
    int lane = tid & 63;
    int b    = blockIdx.x * 4 + wid;
    if (blockIdx.x == 0 && tid == 0) out[0] = 0.f;   // final_k accumulates

    const float* s0 = f + (size_t)(b * 2) * Dd;       // features[b, 0, :]
    float2 x = *(const float2*)(s0 + lane * 2);       // view 0
    float2 y = *(const float2*)(s0 + Dd + lane * 2);  // view 1
    float ss0 = x.x * x.x + x.y * x.y;
    float ss1 = y.x * y.x + y.y * y.y;
    float dt  = x.x * y.x + x.y * y.y;
    #pragma unroll
    for (int off = 32; off; off >>= 1) {
        ss0 += __shfl_xor(ss0, off);
        ss1 += __shfl_xor(ss1, off);
        dt  += __shfl_xor(dt,  off);
    }
    float inv0 = 1.0f / fmaxf(sqrtf(ss0), EPSN);
    float inv1 = 1.0f / fmaxf(sqrtf(ss1), EPSN);
    __hip_bfloat162 h;
    h.x = __float2bfloat16(x.x * inv0);
    h.y = __float2bfloat16(x.y * inv0);
    *(__hip_bfloat162*)(nB + (size_t)b * Dd + lane * 2) = h;
    h.x = __float2bfloat16(x.x * inv0 * SCALE);
    h.y = __float2bfloat16(x.y * inv0 * SCALE);
    *(__hip_bfloat162*)(nA + (size_t)b * Dd + lane * 2) = h;
    h.x = __float2bfloat16(y.x * inv1);
    h.y = __float2bfloat16(y.y * inv1);
    *(__hip_bfloat162*)(nB + (size_t)(Bsz + b) * Dd + lane * 2) = h;
    h.x = __float2bfloat16(y.x * inv1 * SCALE);
    h.y = __float2bfloat16(y.y * inv1 * SCALE);
    *(__hip_bfloat162*)(nA + (size_t)(Bsz + b) * Dd + lane * 2) = h;

    if (lane == 0) sred[wid] = dt * inv0 * inv1 / TEMPf;
    __syncthreads();
    if (tid == 0) sposPart[blockIdx.x] = sred[0] + sred[1] + sred[2] + sred[3];
}

// ------------- main: symmetric fused nA·nB^T -> exp2 -> row+col sums -----------
// 528 blocks = upper-tri (gi<=gj) pairs of 256-row groups. Block computes the
// 256x256 tile S[gi,gj]; row-sums -> partial[gj][rows of gi]; col-sums ->
// partial[gi][rows of gj] (skipped when gi==gj: tile is symmetric, row==col).
// Wave: 64 rows x 256 cols over 4 64-col LDS tiles, double-buffered.
__global__ __launch_bounds__(256, 2)
void main_k(const __hip_bfloat16* __restrict__ nA, const __hip_bfloat16* __restrict__ nB,
            float* __restrict__ partial) {
    __shared__ char lds[2][TILE_BYTES];   // 32 KB
    const int tid  = threadIdx.x;
    const int wid  = tid >> 6;
    const int lane = tid & 63;
    const int lo   = lane & 31;
    const int hi   = lane >> 5;

    // linear block -> (gi, gj), gi <= gj
    int bb = blockIdx.x, gi = 0;
    while (bb >= G - gi) { bb -= G - gi; gi++; }
    const int gj = gi + bb;
    const bool diag = (gi == gj);

    const int rbase = gi * 256 + wid * 64;            // wave's 64 rows
    const char* abytes = (const char*)nA;             // 256 B per row
    const char* gb = (const char*)nB + (size_t)gj * 256 * 256;  // col-group base
    const int su = tid & 15, scb = tid >> 4;          // staging u / col-quad

    // prefetch tile 0 (flat-contiguous, fully coalesced)
    uint4 pf[4];
    #pragma unroll
    for (int i = 0; i < 4; i++)
        pf[i] = *(const uint4*)(gb + i * 4096 + tid * 16);

    // A fragments: row = rbase + s*32 + lo, k-bytes = kc*32 + hi*16
    bf16x8 afrag[2][8];
    #pragma unroll
    for (int s = 0; s < 2; s++) {
        const char* rowp = abytes + (size_t)(rbase + s * 32 + lo) * 256 + hi * 16;
        #pragma unroll
        for (int kc = 0; kc < 8; kc++)
            afrag[s][kc] = *(const bf16x8*)(rowp + kc * 32);
    }

    #pragma unroll
    for (int i = 0; i < 4; i++) {   // write tile 0
        int c = i * 16 + scb;
        *(uint4*)&lds[0][su * 1024 + ((c ^ su) & 63) * 16] = pf[i];
    }
    __syncthreads();

    float sums[2][16];               // row-sum accumulators
    #pragma unroll
    for (int s = 0; s < 2; s++)
        #pragma unroll
        for (int r = 0; r < 16; r++) sums[s][r] = 0.f;
    float csum[4][2];                // col-sum accumulators [tile][cg]
    #pragma unroll
    for (int t = 0; t < 4; t++) { csum[t][0] = 0.f; csum[t][1] = 0.f; }

    floatx16 zero = {};

    #pragma unroll
    for (int t = 0; t < 4; t++) {
        if (t < 3) {                 // prefetch next tile into VGPRs
            const char* g = gb + (size_t)(t + 1) * TILE_BYTES;
            #pragma unroll
            for (int i = 0; i < 4; i++)
                pf[i] = *(const uint4*)(g + i * 4096 + tid * 16);
        }

        const char* buf = lds[t & 1];
        floatx16 acc[2][2];          // [s row-half][cg col-group]
        acc[0][0] = zero; acc[0][1] = zero; acc[1][0] = zero; acc[1][1] = zero;
        #pragma unroll
        for (int kc = 0; kc < 8; kc++) {
            int u = kc * 2 + hi;
            int a0 = u * 1024 + ((lo ^ u) & 63) * 16;
            bf16x8 b0 = *(const bf16x8*)&buf[a0];        // cols lo       (cg=0)
            bf16x8 b1 = *(const bf16x8*)&buf[a0 ^ 512];  // cols lo + 32  (cg=1)
            acc[0][0] = __builtin_amdgcn_mfma_f32_32x32x16_bf16(afrag[0][kc], b0, acc[0][0], 0, 0, 0);
            acc[1][0] = __builtin_amdgcn_mfma_f32_32x32x16_bf16(afrag[1][kc], b0, acc[1][0], 0, 0, 0);
            acc[0][1] = __builtin_amdgcn_mfma_f32_32x32x16_bf16(afrag[0][kc], b1, acc[0][1], 0, 0, 0);
            acc[1][1] = __builtin_amdgcn_mfma_f32_32x32x16_bf16(afrag[1][kc], b1, acc[1][1], 0, 0, 0);
        }

        // epilogue: exp2 (SCALE folded into A), diag mask, row+col accumulate
        const bool dt_hit = diag && (t == wid);
        #pragma unroll
        for (int s = 0; s < 2; s++)
            #pragma unroll
            for (int cg = 0; cg < 2; cg++) {
                #pragma unroll
                for (int r = 0; r < 16; r++) {
                    float e = __builtin_amdgcn_exp2f(acc[s][cg][r]);
                    // C/D layout: col=cg*32+lo, row=s*32+(r&3)+8*(r>>2)+4*hi
                    if (dt_hit && cg == s && lo == ((r & 3) + 8 * (r >> 2) + 4 * hi))
                        e = 0.f;
                    sums[s][r]  += e;
                    csum[t][cg] += e;
                }
            }

        if (t < 3) {                 // write prefetched tile to other buffer
            char* wb = lds[(t + 1) & 1];
            #pragma unroll
            for (int i = 0; i < 4; i++) {
                int c = i * 16 + scb;
                *(uint4*)&wb[su * 1024 + ((c ^ su) & 63) * 16] = pf[i];
            }
        }
        __syncthreads();
    }

    // ---- row sums: reduce across the 32 col-lanes; write partial[gj][rows gi]
    #pragma unroll
    for (int s = 0; s < 2; s++)
        #pragma unroll
        for (int r = 0; r < 16; r++) {
            float v = sums[s][r];
            #pragma unroll
            for (int off = 1; off < 32; off <<= 1) v += __shfl_xor(v, off);
            sums[s][r] = v;
        }
    if (lo == 0) {
        float* prow = partial + (size_t)gj * Nrows;
        #pragma unroll
        for (int s = 0; s < 2; s++)
            #pragma unroll
            for (int r = 0; r < 16; r++) {
                int grow = rbase + s * 32 + (r & 3) + 8 * (r >> 2) + 4 * hi;
                prow[grow] = sums[s][r];
            }
    }

    // ---- col sums (skip on diagonal blocks): cross-wave reduce via LDS
    if (!diag) {
        float* colred = (float*)lds[0];   // [4 waves][256 cols] = 4 KB
        #pragma unroll
        for (int t = 0; t < 4; t++)
            #pragma unroll
            for (int cg = 0; cg < 2; cg++)
                csum[t][cg] += __shfl_xor(csum[t][cg], 32);   // fold hi halves
        if (hi == 0) {
            #pragma unroll
            for (int t = 0; t < 4; t++)
                #pragma unroll
                for (int cg = 0; cg < 2; cg++)
                    colred[wid * 256 + t * 64 + cg * 32 + lo] = csum[t][cg];
        }
        __syncthreads();
        float v = colred[tid] + colred[256 + tid] + colred[512 + tid] + colred[768 + tid];
        partial[(size_t)gi * Nrows + gj * 256 + tid] = v;
    }
}

// ------------- finalize: 32 blocks; atomicAdd the scalar -----------------------
__global__ __launch_bounds__(256)
void final_k(const float* __restrict__ partial, const float* __restrict__ sposPart,
             float* __restrict__ out) {
    __shared__ float red[4];
    int g = blockIdx.x, tid = threadIdx.x;
    int r = g * 256 + tid;
    float se = 0.f;
    #pragma unroll
    for (int p = 0; p < G; p++) se += partial[(size_t)p * Nrows + r];
    float acc = __builtin_amdgcn_logf(se) * LN2;   // v_log_f32 is log2
    if (tid < 32) acc -= 2.f * sposPart[g * 32 + tid];
    #pragma unroll
    for (int off = 32; off; off >>= 1) acc += __shfl_xor(acc, off);
    if ((tid & 63) == 0) red[tid >> 6] = acc;
    __syncthreads();
    if (tid == 0)
        atomicAdd(out, (red[0] + red[1] + red[2] + red[3]) / (float)Nrows);
}

extern "C" void kernel_launch(void* const* d_in, const int* in_sizes, int n_in,
                              void* d_out, int out_size, void* d_ws, size_t ws_size,
                              hipStream_t stream) {
    const float* f = (const float*)d_in[0];
    char* ws = (char*)d_ws;
    __hip_bfloat16* nB = (__hip_bfloat16*)ws;
    __hip_bfloat16* nA = (__hip_bfloat16*)(ws + OFF_NA);
    float* partial     = (float*)(ws + OFF_PART);
    float* sposPart    = (float*)(ws + OFF_SPOS);

    prep_k<<<PREPBLKS, 256, 0, stream>>>(f, nB, nA, sposPart, (float*)d_out);
    main_k<<<NBLK, 256, 0, stream>>>(nA, nB, partial);
    final_k<<<G, 256, 0, stream>>>(partial, sposPart, (float*)d_out);
}

// Round 6
// 99.263 us; speedup vs baseline: 1.3968x; 1.3968x over previous
//
#include <hip/hip_runtime.h>
#include <hip/hip_bf16.h>
#include <math.h>

// SupConLoss, B=4096 V=2 D=128, N=8192.
// loss = (1/N) [ sum_i log(sum_{j!=i} exp(n_i.n_j/T)) - 2*sum_b spos_b ]
// Round 6: symmetric triangular tiling at FINE granularity to kill the R5
// register spill (R5: WRITE_SIZE 68 MB = scratch traffic, 2.6x slowdown).
// 2080 blocks of 128x128; per-wave live state ~105 VGPRs (no spill);
// single-buffered 16 KB LDS; parallel final_k with atomicAdd (no fences).

constexpr int   Bsz   = 4096;
constexpr int   Nrows = 8192;
constexpr int   Dd    = 128;
constexpr float TEMPf = 0.07f;
constexpr float EPSN  = 1e-8f;
constexpr float SCALE = 1.4426950408889634f / 0.07f;  // log2(e)/T
constexpr float LN2   = 0.6931471805599453f;

constexpr int G        = 64;               // row groups of 128
constexpr int GR       = 128;              // rows per group
constexpr int NBLK     = G * (G + 1) / 2;  // 2080 upper-tri pairs
constexpr int PREPBLKS = Bsz / 4;          // 1024

typedef __attribute__((ext_vector_type(8)))  short bf16x8;   // 8 bf16 = 4 VGPRs
typedef __attribute__((ext_vector_type(16))) float floatx16; // MFMA 32x32 C/D

// ws layout (bytes):
//   0x000000  nB   bf16[8192][128]   2 MB
//   0x200000  nA   bf16[8192][128]   2 MB  (pre-scaled by SCALE)
//   0x400000  partial f32[64][8192]  2 MB  (slot = partner group)
//   0x600000  sposPart f32[1024]     4 KB
constexpr size_t OFF_NA   = 0x200000;
constexpr size_t OFF_PART = 0x400000;
constexpr size_t OFF_SPOS = 0x600000;

// ------------- prep: normalize both views + per-block spos sums ----------------
__global__ void prep_k(const float* __restrict__ f,
                       __hip_bfloat16* __restrict__ nB,
                       __hip_bfloat16* __restrict__ nA,
                       float* __restrict__ sposPart,
                       float* __restrict__ out) {
    __shared__ float sred[4];
    int tid  = threadIdx.x;
    int wid  = tid >> 6;
    int lane = tid & 63;
    int b    = blockIdx.x * 4 + wid;
    if (blockIdx.x == 0 && tid == 0) out[0] = 0.f;   // final_k accumulates

    const float* s0 = f + (size_t)(b * 2) * Dd;       // features[b, 0, :]
    float2 x = *(const float2*)(s0 + lane * 2);       // view 0
    float2 y = *(const float2*)(s0 + Dd + lane * 2);  // view 1
    float ss0 = x.x * x.x + x.y * x.y;
    float ss1 = y.x * y.x + y.y * y.y;
    float dt  = x.x * y.x + x.y * y.y;
    #pragma unroll
    for (int off = 32; off; off >>= 1) {
        ss0 += __shfl_xor(ss0, off);
        ss1 += __shfl_xor(ss1, off);
        dt  += __shfl_xor(dt,  off);
    }
    float inv0 = 1.0f / fmaxf(sqrtf(ss0), EPSN);
    float inv1 = 1.0f / fmaxf(sqrtf(ss1), EPSN);
    __hip_bfloat162 h;
    h.x = __float2bfloat16(x.x * inv0);
    h.y = __float2bfloat16(x.y * inv0);
    *(__hip_bfloat162*)(nB + (size_t)b * Dd + lane * 2) = h;
    h.x = __float2bfloat16(x.x * inv0 * SCALE);
    h.y = __float2bfloat16(x.y * inv0 * SCALE);
    *(__hip_bfloat162*)(nA + (size_t)b * Dd + lane * 2) = h;
    h.x = __float2bfloat16(y.x * inv1);
    h.y = __float2bfloat16(y.y * inv1);
    *(__hip_bfloat162*)(nB + (size_t)(Bsz + b) * Dd + lane * 2) = h;
    h.x = __float2bfloat16(y.x * inv1 * SCALE);
    h.y = __float2bfloat16(y.y * inv1 * SCALE);
    *(__hip_bfloat162*)(nA + (size_t)(Bsz + b) * Dd + lane * 2) = h;

    if (lane == 0) sred[wid] = dt * inv0 * inv1 / TEMPf;
    __syncthreads();
    if (tid == 0) sposPart[blockIdx.x] = sred[0] + sred[1] + sred[2] + sred[3];
}

// ------------- main: symmetric fused nA·nB^T -> exp2 -> row+col sums -----------
// 2080 blocks = upper-tri (gi<=gj) pairs of 128-row groups; block computes the
// 128x128 tile. Row-sums -> partial[gj][rows of gi]; col-sums -> partial[gi]
// [rows of gj] (skipped when gi==gj: symmetric tile, row==col).
// Wave w covers rows gi*128+w*32..+31, all 128 cols (two 64-col LDS tiles).
__global__ __launch_bounds__(256, 3)
void main_k(const __hip_bfloat16* __restrict__ nA, const __hip_bfloat16* __restrict__ nB,
            float* __restrict__ partial) {
    __shared__ char lds[64 * 256];   // 16 KB, single-buffered B tile
    const int tid  = threadIdx.x;
    const int wid  = tid >> 6;
    const int lane = tid & 63;
    const int lo   = lane & 31;
    const int hi   = lane >> 5;

    // linear block -> (gi, gj), gi <= gj
    int bb = blockIdx.x, gi = 0;
    while (bb >= G - gi) { bb -= G - gi; gi++; }
    const int gj = gi + bb;
    const bool diag = (gi == gj);

    const int rbase = gi * GR + wid * 32;             // wave's 32 rows
    const char* gb = (const char*)nB + (size_t)gj * GR * 256;  // col-group base
    const int su = tid & 15, scq = tid >> 4;          // staging u / col-16

    // A fragments: row = rbase + lo, k-bytes = kc*32 + hi*16  (32 VGPRs)
    bf16x8 afrag[8];
    {
        const char* rowp = (const char*)nA + (size_t)(rbase + lo) * 256 + hi * 16;
        #pragma unroll
        for (int kc = 0; kc < 8; kc++)
            afrag[kc] = *(const bf16x8*)(rowp + kc * 32);
    }

    float sums[16];                  // row-sum accumulators
    #pragma unroll
    for (int r = 0; r < 16; r++) sums[r] = 0.f;
    float csum[2][2] = {{0.f, 0.f}, {0.f, 0.f}};   // col sums [tile][cg]

    floatx16 zero = {};

    #pragma unroll
    for (int t = 0; t < 2; t++) {
        __syncthreads();
        {   // stage 64-col tile t: 64 B/thread, fully coalesced global reads
            const char* g = gb + t * 16384 + tid * 16;
            #pragma unroll
            for (int i = 0; i < 4; i++) {
                uint4 d = *(const uint4*)(g + i * 4096);
                int c = i * 16 + scq;
                *(uint4*)&lds[su * 1024 + ((c ^ su) & 63) * 16] = d;
            }
        }
        __syncthreads();

        floatx16 acc0 = zero, acc1 = zero;
        #pragma unroll
        for (int kc = 0; kc < 8; kc++) {
            int u = kc * 2 + hi;
            int a0 = u * 1024 + ((lo ^ u) & 63) * 16;
            bf16x8 b0 = *(const bf16x8*)&lds[a0];        // cols lo      (cg=0)
            bf16x8 b1 = *(const bf16x8*)&lds[a0 ^ 512];  // cols lo + 32 (cg=1)
            acc0 = __builtin_amdgcn_mfma_f32_32x32x16_bf16(afrag[kc], b0, acc0, 0, 0, 0);
            acc1 = __builtin_amdgcn_mfma_f32_32x32x16_bf16(afrag[kc], b1, acc1, 0, 0, 0);
        }

        // epilogue: exp2 (SCALE folded into A), diag mask, row+col accumulate
        #pragma unroll
        for (int cg = 0; cg < 2; cg++) {
            const floatx16& acc = cg ? acc1 : acc0;
            // diag hit: col t*64+cg*32+lo == row wid*32+row_local
            bool dt_hit = diag && (wid == t * 2 + cg);
            #pragma unroll
            for (int r = 0; r < 16; r++) {
                float e = __builtin_amdgcn_exp2f(acc[r]);
                // C/D layout (m74/m101): col=lo(+cg*32), row_local=(r&3)+8*(r>>2)+4*hi
                if (dt_hit && lo == ((r & 3) + 8 * (r >> 2) + 4 * hi)) e = 0.f;
                sums[r]      += e;
                csum[t][cg]  += e;
            }
        }
    }

    // ---- row sums: reduce across 32 col-lanes; write partial[gj][rows of gi]
    #pragma unroll
    for (int r = 0; r < 16; r++) {
        float v = sums[r];
        #pragma unroll
        for (int off = 1; off < 32; off <<= 1) v += __shfl_xor(v, off);
        sums[r] = v;
    }
    if (lo == 0) {
        float* prow = partial + (size_t)gj * Nrows;
        #pragma unroll
        for (int r = 0; r < 16; r++) {
            int grow = rbase + (r & 3) + 8 * (r >> 2) + 4 * hi;
            prow[grow] = sums[r];
        }
    }

    // ---- col sums (skip on diagonal blocks): cross-wave reduce via LDS
    if (!diag) {
        __syncthreads();               // everyone done with the B tile
        float* colred = (float*)lds;   // [4 waves][128 cols] = 2 KB
        #pragma unroll
        for (int t = 0; t < 2; t++)
            #pragma unroll
            for (int cg = 0; cg < 2; cg++)
                csum[t][cg] += __shfl_xor(csum[t][cg], 32);   // fold hi halves
        if (hi == 0) {
            #pragma unroll
            for (int t = 0; t < 2; t++)
                #pragma unroll
                for (int cg = 0; cg < 2; cg++)
                    colred[wid * 128 + t * 64 + cg * 32 + lo] = csum[t][cg];
        }
        __syncthreads();
        if (tid < 128) {
            float v = colred[tid] + colred[128 + tid]
                    + colred[256 + tid] + colred[384 + tid];
            partial[(size_t)gi * Nrows + gj * GR + tid] = v;
        }
    }
}

// ------------- finalize: 32 blocks; atomicAdd the scalar -----------------------
__global__ __launch_bounds__(256)
void final_k(const float* __restrict__ partial, const float* __restrict__ sposPart,
             float* __restrict__ out) {
    __shared__ float red[4];
    int tid = threadIdx.x;
    int r = blockIdx.x * 256 + tid;
    float se = 0.f;
    #pragma unroll
    for (int p = 0; p < G; p++) se += partial[(size_t)p * Nrows + r];
    float acc = __builtin_amdgcn_logf(se) * LN2;   // v_log_f32 is log2
    if (tid < 32) acc -= 2.f * sposPart[blockIdx.x * 32 + tid];
    #pragma unroll
    for (int off = 32; off; off >>= 1) acc += __shfl_xor(acc, off);
    if ((tid & 63) == 0) red[tid >> 6] = acc;
    __syncthreads();
    if (tid == 0)
        atomicAdd(out, (red[0] + red[1] + red[2] + red[3]) / (float)Nrows);
}

extern "C" void kernel_launch(void* const* d_in, const int* in_sizes, int n_in,
                              void* d_out, int out_size, void* d_ws, size_t ws_size,
                              hipStream_t stream) {
    const float* f = (const float*)d_in[0];
    char* ws = (char*)d_ws;
    __hip_bfloat16* nB = (__hip_bfloat16*)ws;
    __hip_bfloat16* nA = (__hip_bfloat16*)(ws + OFF_NA);
    float* partial     = (float*)(ws + OFF_PART);
    float* sposPart    = (float*)(ws + OFF_SPOS);

    prep_k<<<PREPBLKS, 256, 0, stream>>>(f, nB, nA, sposPart, (float*)d_out);
    main_k<<<NBLK, 256, 0, stream>>>(nA, nB, partial);
    final_k<<<Nrows / 256, 256, 0, stream>>>(partial, sposPart, (float*)d_out);
}

// Round 7
// 82.488 us; speedup vs baseline: 1.6809x; 1.2034x over previous
//
#include <hip/hip_runtime.h>
#include <hip/hip_bf16.h>
#include <math.h>

// SupConLoss, B=4096 V=2 D=128, N=8192.
// loss = (1/N) [ sum_i log(sum_{j!=i} exp(n_i.n_j/T)) - 2*sum_b spos_b ]
// Round 7: occupancy attack. R2-R6 evidence: main_k is latency-bound at
// 2 waves/SIMD (Occupancy 14%, all pipes <10%). Keep per-wave total regs
// (arch+acc, unified file) <= 128 so 4 waves/SIMD x 4 blocks/CU co-reside.
// Wave tile 32 rows x 64 cols; block 128 rows x 512 cols; 1024 blocks.
// No symmetry (R6: per-block overhead beats the 2x FLOP saving).

constexpr int   Bsz   = 4096;
constexpr int   Nrows = 8192;
constexpr int   Dd    = 128;
constexpr float TEMPf = 0.07f;
constexpr float EPSN  = 1e-8f;
constexpr float SCALE = 1.4426950408889634f / 0.07f;  // log2(e)/T
constexpr float LN2   = 0.6931471805599453f;

constexpr int CHUNKS     = 16;                     // col chunks (grid.x)
constexpr int CHUNK_COLS = Nrows / CHUNKS;         // 512
constexpr int TILE_COLS  = 64;
constexpr int TILES      = CHUNK_COLS / TILE_COLS; // 8
constexpr int ROWS_BLK   = 128;                    // rows per block (grid.y=64)
constexpr int PREPBLKS   = Bsz / 4;                // 1024

typedef __attribute__((ext_vector_type(8)))  short bf16x8;   // 8 bf16 = 4 VGPRs
typedef __attribute__((ext_vector_type(16))) float floatx16; // MFMA 32x32 C/D

// ws layout (bytes):
//   0x000000  nB   bf16[8192][128]   2 MB
//   0x200000  nA   bf16[8192][128]   2 MB  (pre-scaled by SCALE)
//   0x400000  partial f32[16][8192]  512 KB
//   0x480000  sposPart f32[1024]     4 KB
constexpr size_t OFF_NA   = 0x200000;
constexpr size_t OFF_PART = 0x400000;
constexpr size_t OFF_SPOS = 0x480000;

// ------------- prep: normalize both views + per-block spos sums ----------------
__global__ void prep_k(const float* __restrict__ f,
                       __hip_bfloat16* __restrict__ nB,
                       __hip_bfloat16* __restrict__ nA,
                       float* __restrict__ sposPart,
                       float* __restrict__ out) {
    __shared__ float sred[4];
    int tid  = threadIdx.x;
    int wid  = tid >> 6;
    int lane = tid & 63;
    int b    = blockIdx.x * 4 + wid;
    if (blockIdx.x == 0 && tid == 0) out[0] = 0.f;   // final_k accumulates

    const float* s0 = f + (size_t)(b * 2) * Dd;       // features[b, 0, :]
    float2 x = *(const float2*)(s0 + lane * 2);       // view 0
    float2 y = *(const float2*)(s0 + Dd + lane * 2);  // view 1
    float ss0 = x.x * x.x + x.y * x.y;
    float ss1 = y.x * y.x + y.y * y.y;
    float dt  = x.x * y.x + x.y * y.y;
    #pragma unroll
    for (int off = 32; off; off >>= 1) {
        ss0 += __shfl_xor(ss0, off);
        ss1 += __shfl_xor(ss1, off);
        dt  += __shfl_xor(dt,  off);
    }
    float inv0 = 1.0f / fmaxf(sqrtf(ss0), EPSN);
    float inv1 = 1.0f / fmaxf(sqrtf(ss1), EPSN);
    __hip_bfloat162 h;
    h.x = __float2bfloat16(x.x * inv0);
    h.y = __float2bfloat16(x.y * inv0);
    *(__hip_bfloat162*)(nB + (size_t)b * Dd + lane * 2) = h;
    h.x = __float2bfloat16(x.x * inv0 * SCALE);
    h.y = __float2bfloat16(x.y * inv0 * SCALE);
    *(__hip_bfloat162*)(nA + (size_t)b * Dd + lane * 2) = h;
    h.x = __float2bfloat16(y.x * inv1);
    h.y = __float2bfloat16(y.y * inv1);
    *(__hip_bfloat162*)(nB + (size_t)(Bsz + b) * Dd + lane * 2) = h;
    h.x = __float2bfloat16(y.x * inv1 * SCALE);
    h.y = __float2bfloat16(y.y * inv1 * SCALE);
    *(__hip_bfloat162*)(nA + (size_t)(Bsz + b) * Dd + lane * 2) = h;

    if (lane == 0) sred[wid] = dt * inv0 * inv1 / TEMPf;
    __syncthreads();
    if (tid == 0) sposPart[blockIdx.x] = sred[0] + sred[1] + sred[2] + sred[3];
}

// ------------- main: fused nA·nB^T -> exp2 -> per-chunk row sums ---------------
// Block: 256 thr (4 waves), 128 rows x 512 cols. Wave w: rows by*128+w*32..+31.
// 8 tiles of 64 cols staged through 16 KB LDS ([u][c^u] swizzle, conflict-free
// b128 reads). Per-wave regs ~116 incl. 32 acc -> 4 waves/SIMD, 4 blocks/CU.
__global__ __launch_bounds__(256, 4)
void main_k(const __hip_bfloat16* __restrict__ nA, const __hip_bfloat16* __restrict__ nB,
            float* __restrict__ partial) {
    __shared__ char lds[TILE_COLS * 256];   // 16 KB
    const int tid  = threadIdx.x;
    const int wid  = tid >> 6;
    const int lane = tid & 63;
    const int lo   = lane & 31;
    const int hi   = lane >> 5;
    const int rbase = blockIdx.y * ROWS_BLK + wid * 32;  // wave's 32 rows
    const int cbase = blockIdx.x * CHUNK_COLS;
    const char* gb  = (const char*)nB + (size_t)cbase * 256;
    const int su = tid & 15, scq = tid >> 4;             // staging u / col-16

    // A fragments: row = rbase + lo, k-bytes = kc*32 + hi*16  (32 VGPRs)
    bf16x8 afrag[8];
    {
        const char* rowp = (const char*)nA + (size_t)(rbase + lo) * 256 + hi * 16;
        #pragma unroll
        for (int kc = 0; kc < 8; kc++)
            afrag[kc] = *(const bf16x8*)(rowp + kc * 32);
    }

    float sums[16];
    #pragma unroll
    for (int r = 0; r < 16; r++) sums[r] = 0.f;

    floatx16 zero = {};

    #pragma unroll 1   // keep the loop rolled: unrolling spills (R5 lesson)
    for (int t = 0; t < TILES; t++) {
        __syncthreads();
        {   // stage 64-col tile t: 64 B/thread, coalesced 4-KB-stride reads
            const char* g = gb + (size_t)t * (TILE_COLS * 256) + tid * 16;
            #pragma unroll
            for (int i = 0; i < 4; i++) {
                uint4 d = *(const uint4*)(g + i * 4096);
                int c = i * 16 + scq;
                *(uint4*)&lds[su * 1024 + ((c ^ su) & 63) * 16] = d;
            }
        }
        __syncthreads();

        floatx16 acc0 = zero, acc1 = zero;
        #pragma unroll
        for (int kc = 0; kc < 8; kc++) {
            int u = kc * 2 + hi;
            int a0 = u * 1024 + ((lo ^ u) & 63) * 16;
            bf16x8 b0 = *(const bf16x8*)&lds[a0];        // cols lo      (cg=0)
            bf16x8 b1 = *(const bf16x8*)&lds[a0 ^ 512];  // cols lo + 32 (cg=1)
            acc0 = __builtin_amdgcn_mfma_f32_32x32x16_bf16(afrag[kc], b0, acc0, 0, 0, 0);
            acc1 = __builtin_amdgcn_mfma_f32_32x32x16_bf16(afrag[kc], b1, acc1, 0, 0, 0);
        }

        // epilogue: exp2 (SCALE folded into A), diagonal mask, row-sum acc
        #pragma unroll
        for (int cg = 0; cg < 2; cg++) {
            const floatx16& acc = cg ? acc1 : acc0;
            // wave rows are 32-aligned; this 32-col half hits the diagonal iff
            // its global col base equals rbase
            bool dt_hit = (cbase + t * TILE_COLS + cg * 32 == rbase);
            #pragma unroll
            for (int r = 0; r < 16; r++) {
                float e = __builtin_amdgcn_exp2f(acc[r]);
                // C/D layout (m74/m101): col=lo, row_local=(r&3)+8*(r>>2)+4*hi
                if (dt_hit && lo == ((r & 3) + 8 * (r >> 2) + 4 * hi)) e = 0.f;
                sums[r] += e;
            }
        }
    }

    // row sums: reduce across 32 col-lanes; write partial[chunk][row]
    #pragma unroll
    for (int r = 0; r < 16; r++) {
        float v = sums[r];
        #pragma unroll
        for (int off = 1; off < 32; off <<= 1) v += __shfl_xor(v, off);
        sums[r] = v;
    }
    if (lo == 0) {
        float* prow = partial + (size_t)blockIdx.x * Nrows;
        #pragma unroll
        for (int r = 0; r < 16; r++) {
            int grow = rbase + (r & 3) + 8 * (r >> 2) + 4 * hi;
            prow[grow] = sums[r];
        }
    }
}

// ------------- finalize: 32 blocks; atomicAdd the scalar -----------------------
__global__ __launch_bounds__(256)
void final_k(const float* __restrict__ partial, const float* __restrict__ sposPart,
             float* __restrict__ out) {
    __shared__ float red[4];
    int tid = threadIdx.x;
    int r = blockIdx.x * 256 + tid;
    float se = 0.f;
    #pragma unroll
    for (int p = 0; p < CHUNKS; p++) se += partial[(size_t)p * Nrows + r];
    float acc = __builtin_amdgcn_logf(se) * LN2;   // v_log_f32 is log2
    if (tid < 32) acc -= 2.f * sposPart[blockIdx.x * 32 + tid];
    #pragma unroll
    for (int off = 32; off; off >>= 1) acc += __shfl_xor(acc, off);
    if ((tid & 63) == 0) red[tid >> 6] = acc;
    __syncthreads();
    if (tid == 0)
        atomicAdd(out, (red[0] + red[1] + red[2] + red[3]) / (float)Nrows);
}

extern "C" void kernel_launch(void* const* d_in, const int* in_sizes, int n_in,
                              void* d_out, int out_size, void* d_ws, size_t ws_size,
                              hipStream_t stream) {
    const float* f = (const float*)d_in[0];
    char* ws = (char*)d_ws;
    __hip_bfloat16* nB = (__hip_bfloat16*)ws;
    __hip_bfloat16* nA = (__hip_bfloat16*)(ws + OFF_NA);
    float* partial     = (float*)(ws + OFF_PART);
    float* sposPart    = (float*)(ws + OFF_SPOS);

    prep_k<<<PREPBLKS, 256, 0, stream>>>(f, nB, nA, sposPart, (float*)d_out);
    dim3 grid(CHUNKS, Nrows / ROWS_BLK);
    main_k<<<grid, 256, 0, stream>>>(nA, nB, partial);
    final_k<<<Nrows / 256, 256, 0, stream>>>(partial, sposPart, (float*)d_out);
}